// Round 7
// baseline (172.816 us; speedup 1.0000x reference)
//
#include <hip/hip_runtime.h>

// NeuSSampler PDF importance resampling — persistent waves with a DEPTH-3
// rolling register pipeline and a steady state that touches only vmcnt.
//
// Diagnosis history: all prior rounds pinned at 50-60us with VALU<=46%,
// HBM<=24%, occupancy ~65% -> memory-LATENCY(MLP)-bound: each wave kept only
// ~1.3KB outstanding. This version keeps ~3 rays' loads (~3KB) in flight
// continuously, and eliminates every lgkm op from the loop so prefetches are
// never drained:
//   - near/far: lane-gathered VECTOR load (lane0->nears[r], lane1->fars[r];
//     divergent address prevents s_load scalarization), v_readlane after the
//     vm wait. s_load would be out-of-order -> lgkmcnt(0) -> drains future
//     prefetches (round-6 bug).
//   - bins[2l+2] loaded directly per lane (extra dword, same cache line as
//     the float2 in most lanes; lane63 gets bins[128] for free) -> no
//     __shfl_down, no separate b_last scalar.
//   - cdf[2l] = prev lane's cdf edge via DPP wave_shr:1 (pure VALU, no DS);
//     bound_ctrl gives lane0 exactly 0.0f = cdf[0]. Bitwise-identical to
//     lane l-1's c_hi -> the jf() ranges tile [0,65) exactly.
//
// Compute (unchanged from round 3, validated absmax 0.03125): pair-sum DPP
// inclusive scan -> cdf edges in registers; queries u_j=(2j+1)/130 are an
// arithmetic progression, segment k covers j in [jf(cdf[k]), jf(cdf[k+1])),
// jf(c)=ceil(65c-0.5); per segment one v_rcp + incremental t. Degenerate
// d==0 on the forced lane-63 range: t=inf/NaN -> clamp(NaN)=0 / clip(inf)=1
// reproduces the reference's nan_to_num+clip.

#define DPP_FADD(x, ctrl, rmask)                                             \
    ((x) + __int_as_float(__builtin_amdgcn_update_dpp(                       \
               0, __float_as_int(x), (ctrl), (rmask), 0xf, true)))

__global__ __launch_bounds__(256) void neus_sampler_kernel(
    const float* __restrict__ weights,
    const float* __restrict__ bins_g,
    const float* __restrict__ nears,
    const float* __restrict__ fars,
    float* __restrict__ out,
    int R)
{
    constexpr int S  = 128;   // weights per ray
    constexpr int SE = 129;   // bin edges per ray
    constexpr int NB = 65;    // output samples per ray
    constexpr float HPAD = 1e-5f;

    const int lane = threadIdx.x & 63;
    const int gw   = blockIdx.x * 4 + (threadIdx.x >> 6);  // global wave id
    const int nw   = gridDim.x * 4;                        // total waves

    struct Stage { float wx, wy, bx, by, b2, nf; };

    auto issue = [&](int r) -> Stage {
        Stage st;
        const int ur = __builtin_amdgcn_readfirstlane(r);
        const float2 w =
            reinterpret_cast<const float2*>(weights + (size_t)ur * S)[lane];
        st.wx = w.x; st.wy = w.y;
        const float* brow = bins_g + (size_t)ur * SE;
        const float2 b = reinterpret_cast<const float2*>(brow)[lane];
        st.bx = b.x; st.by = b.y;
        st.b2 = brow[2 * lane + 2];              // lane63 -> bins[128]
        const float* pa = (lane == 1) ? (fars + ur) : (nears + ur);
        st.nf = *pa;                             // vector load (divergent addr)
        return st;
    };

    // first query index j with u_j >= c  (u_j = (2j+1)/130)
    auto jf = [](float c) -> int {
        int j = (int)ceilf(fmaf(65.0f, c, -0.5f));
        return j < 0 ? 0 : (j > NB ? NB : j);
    };

    auto compute = [&](const Stage& st, int r) {
        const int ur = __builtin_amdgcn_readfirstlane(r);
        const float w1 = st.wy + HPAD;
        float ps = (st.wx + HPAD) + w1;          // pair sum
        ps = DPP_FADD(ps, 0x111, 0xf);  // row_shr:1
        ps = DPP_FADD(ps, 0x112, 0xf);  // row_shr:2
        ps = DPP_FADD(ps, 0x114, 0xf);  // row_shr:4
        ps = DPP_FADD(ps, 0x118, 0xf);  // row_shr:8
        ps = DPP_FADD(ps, 0x142, 0xa);  // row_bcast:15 -> rows 1,3
        ps = DPP_FADD(ps, 0x143, 0xc);  // row_bcast:31 -> rows 2,3

        const float total = __int_as_float(
            __builtin_amdgcn_readlane(__float_as_int(ps), 63));
        const float padding = fmaxf(1e-5f - total, 0.0f);  // relu(EPS - sum)
        const float padc    = padding * (1.0f / S);
        const float inv     = __builtin_amdgcn_rcpf(total + padding);

        const float c_hi  = fminf(1.0f, fmaf((float)(2*lane+2), padc, ps) * inv);
        const float c_mid = fminf(1.0f, fmaf((float)(2*lane+1), padc, ps - w1) * inv);
        // cdf[2l] = lane l-1's c_hi, bitwise (DPP wave_shr:1); lane0 -> 0.0f
        const float c_lo = __int_as_float(__builtin_amdgcn_update_dpp(
            0, __float_as_int(c_hi), 0x138, 0xf, 0xf, true));

        const float ne = __int_as_float(
            __builtin_amdgcn_readlane(__float_as_int(st.nf), 0));
        const float fa = __int_as_float(
            __builtin_amdgcn_readlane(__float_as_int(st.nf), 1));

        const int j0 = jf(c_lo);
        const int j2 = (lane == 63) ? NB : jf(c_hi);
        int j1 = jf(c_mid);
        j1 = j1 < j0 ? j0 : (j1 > j2 ? j2 : j1); // tile [j0,j2) exactly

        const float fmn = fa - ne;
        float* orow = out + (size_t)ur * NB;

        if (j1 > j0) {                           // segment [c_lo, c_mid)
            const float r1 = __builtin_amdgcn_rcpf(c_mid - c_lo);
            const float dt = r1 * (1.0f / 65.0f);
            const float bd = st.by - st.bx;
            float t = fmaf((float)(2*j0+1), (1.0f/130.0f), -c_lo) * r1;
            for (int j = j0; j < j1; ++j) {
                const float tc = fminf(fmaxf(t, 0.0f), 1.0f);
                orow[j] = fmaf(fmaf(tc, bd, st.bx), fmn, ne);
                t += dt;
            }
        }
        if (j2 > j1) {                           // segment [c_mid, c_hi)
            const float r1 = __builtin_amdgcn_rcpf(c_hi - c_mid);  // inf ok
            const float dt = r1 * (1.0f / 65.0f);
            const float bd = st.b2 - st.by;
            float t = fmaf((float)(2*j1+1), (1.0f/130.0f), -c_mid) * r1;
            for (int j = j1; j < j2; ++j) {
                const float tc = fminf(fmaxf(t, 0.0f), 1.0f);  // NaN-safe ->0
                orow[j] = fmaf(fmaf(tc, bd, st.by), fmn, ne);
                t += dt;
            }
        }
    };

    // ---- depth-3 rolling pipeline over this wave's rays ----
    int ray = gw;
    if (ray >= R) return;                        // wave-uniform
    Stage s0, s1, s2;
    s0 = issue(ray);
    const int r1i = ray + nw, r2i = ray + 2 * nw;
    if (r1i < R) s1 = issue(r1i);
    if (r2i < R) s2 = issue(r2i);

    int nxt = ray + 3 * nw;
    while (true) {
        compute(s0, ray);
        ray += nw;
        if (ray >= R) break;                     // wave-uniform
        s0 = s1; s1 = s2;                        // rotate stages
        if (nxt < R) s2 = issue(nxt);
        nxt += nw;
    }
}

extern "C" void kernel_launch(void* const* d_in, const int* in_sizes, int n_in,
                              void* d_out, int out_size, void* d_ws, size_t ws_size,
                              hipStream_t stream) {
    const float* weights = (const float*)d_in[0];   // [R,128,1]
    const float* ebins   = (const float*)d_in[1];   // [R,129]
    const float* nears   = (const float*)d_in[2];   // [R,1]
    const float* fars    = (const float*)d_in[3];   // [R,1]
    float* out = (float*)d_out;                     // [R,65]
    const int R = in_sizes[0] / 128;
    // Persistent grid: 2048 blocks x 4 waves = 8192 waves (8/SIMD resident);
    // each wave pipelines its 16 rays at depth 3 (~3KB in flight per wave).
    const int blocks = 2048;
    hipLaunchKernelGGL(neus_sampler_kernel, dim3(blocks), dim3(256), 0, stream,
                       weights, ebins, nears, fars, out, R);
}